// Round 2
// baseline (256.264 us; speedup 1.0000x reference)
//
#include <hip/hip_runtime.h>
#include <hip/hip_bf16.h>
#include <math.h>

// Problem constants (B=2, C=256, H=W=64, D=4, K=9, K2=81)
#define BATCH 2
#define CCH   256
#define HH    64
#define WW    64
#define PIX   (HH*WW)          // 4096
#define K2    81
#define BP_N  (BATCH*PIX)      // 8192

// ---------------------------------------------------------------------------
// NCHW -> NHWC tiled transpose, both feature tensors in one launch.
// z = 0,1 -> feat batches; z = 2,3 -> feat_ref batches.
// ---------------------------------------------------------------------------
__global__ void k_transpose2(const float* __restrict__ feat,
                             const float* __restrict__ feat_ref,
                             float* __restrict__ featT,
                             float* __restrict__ refT) {
    __shared__ float tile[32][33];
    int z  = blockIdx.z;
    int b  = z & 1;
    const float* in  = (z >> 1) ? feat_ref : feat;
    float*       out = (z >> 1) ? refT     : featT;
    int p0 = blockIdx.x * 32;
    int c0 = blockIdx.y * 32;
    int tx = threadIdx.x;     // 32
    int ty = threadIdx.y;     // 8
    const float* ib = in  + (size_t)b * CCH * PIX;
    float*       ob = out + (size_t)b * CCH * PIX;
    #pragma unroll
    for (int i = 0; i < 4; i++) {
        int c = c0 + ty + i * 8;
        int p = p0 + tx;
        tile[ty + i * 8][tx] = ib[(size_t)c * PIX + p];
    }
    __syncthreads();
    #pragma unroll
    for (int i = 0; i < 4; i++) {
        int p = p0 + ty + i * 8;
        int c = c0 + tx;
        ob[(size_t)p * CCH + c] = tile[tx][ty + i * 8];
    }
}

// ---------------------------------------------------------------------------
// Weight prep, one launch: blocks 0..127 -> w1t transpose, 128..271 -> w2t.
// w1 [256][512] (o,c) -> w1t [512][256];  w2 [16][256][3][3] -> R12 layout.
// ---------------------------------------------------------------------------
__global__ void k_wprep(const float* __restrict__ w1, float* __restrict__ w1t,
                        const float* __restrict__ w2, float* __restrict__ w2t) {
    __shared__ float tile[32][33];
    int blk = blockIdx.x;
    int tid = threadIdx.x;            // 256 flat
    if (blk < 128) {
        int c0 = (blk & 15) * 32;
        int o0 = (blk >> 4) * 32;
        int tx = tid & 31;
        int ty = tid >> 5;
        #pragma unroll
        for (int i = 0; i < 4; i++)
            tile[ty + i * 8][tx] = w1[(size_t)(o0 + ty + i * 8) * 512 + c0 + tx];
        __syncthreads();
        #pragma unroll
        for (int i = 0; i < 4; i++)
            w1t[(size_t)(c0 + ty + i * 8) * 256 + o0 + tx] = tile[tx][ty + i * 8];
    } else {
        int i = (blk - 128) * 256 + tid;
        if (i < 16 * 256 * 9) {
            int o  = i / 2304;
            int r  = i % 2304;        // c*9 + kk
            int c  = r / 9;
            int kk = r % 9;
            int cg = c >> 2, ci = c & 3;
            w2t[(((kk * 64 + cg) * 16 + o) << 2) + ci] = w2[i];
        }
    }
}

// ---------------------------------------------------------------------------
// Correlation + sum-normalize + assemble — BIT-EXACT recipe (passed R7-R15,
// absmax 16384/19988).  FP op sequence IDENTICAL to R15:
//   phase 1: per-k t=0..7 ascending fmaf chain, butterfly xor 8,16,4,2,1
//   phase 2: sequential ascending-k fp32 add chain over ALL 81 (zeros incl.)
//   phase 3: sequential ascending-valid-k fmaf chain
//
// R16: ILP only — no rounding change.
//  * phase 1: 2 k's per 32-lane group per iteration (16 loads in flight,
//    shuffle reduces interleaved); (k,poff) packed int2 -> 1 ds_read_b64.
//  * phase 3: 8-deep branchless load batches (was 4).
//  * XCD swizzle retained.
// ---------------------------------------------------------------------------
__global__ void k_corr_assemble(const float* __restrict__ featT,
                                const float* __restrict__ refT,
                                float* __restrict__ alignedT) {
    int blk = blockIdx.x;
    int bp  = ((blk & 7) << 10) | (blk >> 3);   // XCD-contiguous pixel bands
    int b  = bp >> 12;
    int p  = bp & 4095;
    int h  = p >> 6, w = p & 63;
    int tid = threadIdx.x;             // 0..255

    __shared__ float s_aff[K2];
    __shared__ __align__(16) float s_affc[88];   // compacted affn (valid k asc)
    __shared__ __align__(16) int   s_poff[88];   // compacted pix byte-offsets
    __shared__ __align__(8)  int2  s_kp[88];     // compacted (k, poff)
    __shared__ int   s_hi_k[24];
    __shared__ int   s_hi_o[24];
    __shared__ int   s_cnt0, s_cnt1;
    __shared__ float s_den;

    int hw = tid >> 5;        // 0..7
    int j  = tid & 31;        // 0..31

    // feat fragment in registers (same values as old s_feat[32t+j])
    const float* fb = featT + ((size_t)bp << 8) + j;
    float f0 = fb[0],   f1 = fb[32],  f2 = fb[64],  f3 = fb[96];
    float f4 = fb[128], f5 = fb[160], f6 = fb[192], f7 = fb[224];

    if (tid < K2) s_aff[tid] = 0.f;    // invalid k stay exactly +0 for phase 2

    // --- build compacted (k,poff) list, order-preserving (ballot+prefix) ---
    if (tid < 128) {
        int k  = tid;
        int dy = k / 9, dx = k - dy * 9;
        int y  = h + dy - 4, x = w + dx - 4;
        bool valid = (k < K2) && ((unsigned)y < 64u) && ((unsigned)x < 64u);
        int poff = valid ? (((y << 6) | x) << 10) : 0;   // pix*256*4 bytes
        unsigned long long m = __ballot(valid);
        int lane   = tid & 63;
        int prefix = __popcll(m & ((1ULL << lane) - 1ULL));
        if (tid < 64) {
            if (valid) s_kp[prefix] = make_int2(k, poff);
            if (tid == 0) s_cnt0 = (int)__popcll(m);
        } else {
            if (valid) { s_hi_k[prefix] = k; s_hi_o[prefix] = poff; }
            if (tid == 64) s_cnt1 = (int)__popcll(m);
        }
    }
    __syncthreads();
    int n0 = s_cnt0, n1 = s_cnt1;
    int nv = n0 + n1;                  // uniform across block
    if (tid < n1) s_kp[n0 + tid] = make_int2(s_hi_k[tid], s_hi_o[tid]);
    __syncthreads();
    if (tid < nv) s_poff[tid] = s_kp[tid].y;   // for phase 3 (read much later)

    const float* rb  = refT + ((size_t)b << 20);   // b*4096*256
    const char*  rbj = (const char*)rb + 4 * j;

    // Phase 1: 2 k's per group-iteration; per-k FP chain unchanged.
    for (int ii = 2 * hw; ii < nv; ii += 16) {
        int2 kp0 = s_kp[ii];
        bool has1 = (ii + 1) < nv;
        int2 kp1 = has1 ? s_kp[ii + 1] : kp0;
        const char* rp0 = rbj + kp0.y;
        const char* rp1 = rbj + kp1.y;
        float pa = 0.f, pb = 0.f;
        pa = fmaf(f0, *(const float*)(rp0 +   0), pa);
        pb = fmaf(f0, *(const float*)(rp1 +   0), pb);
        pa = fmaf(f1, *(const float*)(rp0 + 128), pa);
        pb = fmaf(f1, *(const float*)(rp1 + 128), pb);
        pa = fmaf(f2, *(const float*)(rp0 + 256), pa);
        pb = fmaf(f2, *(const float*)(rp1 + 256), pb);
        pa = fmaf(f3, *(const float*)(rp0 + 384), pa);
        pb = fmaf(f3, *(const float*)(rp1 + 384), pb);
        pa = fmaf(f4, *(const float*)(rp0 + 512), pa);
        pb = fmaf(f4, *(const float*)(rp1 + 512), pb);
        pa = fmaf(f5, *(const float*)(rp0 + 640), pa);
        pb = fmaf(f5, *(const float*)(rp1 + 640), pb);
        pa = fmaf(f6, *(const float*)(rp0 + 768), pa);
        pb = fmaf(f6, *(const float*)(rp1 + 768), pb);
        pa = fmaf(f7, *(const float*)(rp0 + 896), pa);
        pb = fmaf(f7, *(const float*)(rp1 + 896), pb);
        pa = __fadd_rn(pa, __shfl_xor(pa, 8));
        pb = __fadd_rn(pb, __shfl_xor(pb, 8));
        pa = __fadd_rn(pa, __shfl_xor(pa, 16));
        pb = __fadd_rn(pb, __shfl_xor(pb, 16));
        pa = __fadd_rn(pa, __shfl_xor(pa, 4));
        pb = __fadd_rn(pb, __shfl_xor(pb, 4));
        pa = __fadd_rn(pa, __shfl_xor(pa, 2));
        pb = __fadd_rn(pb, __shfl_xor(pb, 2));
        pa = __fadd_rn(pa, __shfl_xor(pa, 1));
        pb = __fadd_rn(pb, __shfl_xor(pb, 1));
        if (j == 0) {
            s_aff[kp0.x] = pa;
            if (has1) s_aff[kp1.x] = pb;
        }
    }
    __syncthreads();

    // Phase 2: sequential ascending-k fp32 add chain over ALL 81
    if (tid == 0) {
        float s = 0.f;
        for (int k = 0; k < K2; k++) s = __fadd_rn(s, s_aff[k]);
        s_den = __fadd_rn(s, 1e-7f);
    }
    __syncthreads();
    if (tid < nv) s_affc[tid] = __fdiv_rn(s_aff[s_kp[tid].x], s_den);
    __syncthreads();

    // Phase 3: sequential ascending-valid-k FMA chain, 8-deep load batches.
    const char* rbc = (const char*)rb + ((size_t)tid << 2);
    float acc = 0.f;
    int i = 0;
    for (; i + 8 <= nv; i += 8) {
        float4 af0 = *(const float4*)&s_affc[i];
        float4 af1 = *(const float4*)&s_affc[i + 4];
        int4   po0 = *(const int4*)&s_poff[i];
        int4   po1 = *(const int4*)&s_poff[i + 4];
        float v0 = *(const float*)(rbc + po0.x);
        float v1 = *(const float*)(rbc + po0.y);
        float v2 = *(const float*)(rbc + po0.z);
        float v3 = *(const float*)(rbc + po0.w);
        float v4 = *(const float*)(rbc + po1.x);
        float v5 = *(const float*)(rbc + po1.y);
        float v6 = *(const float*)(rbc + po1.z);
        float v7 = *(const float*)(rbc + po1.w);
        acc = fmaf(af0.x, v0, acc);
        acc = fmaf(af0.y, v1, acc);
        acc = fmaf(af0.z, v2, acc);
        acc = fmaf(af0.w, v3, acc);
        acc = fmaf(af1.x, v4, acc);
        acc = fmaf(af1.y, v5, acc);
        acc = fmaf(af1.z, v6, acc);
        acc = fmaf(af1.w, v7, acc);
    }
    if (i + 4 <= nv) {
        float4 af = *(const float4*)&s_affc[i];
        int4   po = *(const int4*)&s_poff[i];
        float v0 = *(const float*)(rbc + po.x);
        float v1 = *(const float*)(rbc + po.y);
        float v2 = *(const float*)(rbc + po.z);
        float v3 = *(const float*)(rbc + po.w);
        acc = fmaf(af.x, v0, acc);
        acc = fmaf(af.y, v1, acc);
        acc = fmaf(af.z, v2, acc);
        acc = fmaf(af.w, v3, acc);
        i += 4;
    }
    for (; i < nv; i++)
        acc = fmaf(s_affc[i], *(const float*)(rbc + s_poff[i]), acc);
    alignedT[((size_t)bp << 8) + tid] = acc;
}

// ---------------------------------------------------------------------------
// Conv1: 1x1, 512 -> 256, FP32 GEMM (numerics-free).  Verbatim from R13.
// ---------------------------------------------------------------------------
__global__ void k_conv1(const float* __restrict__ featT,
                        const float* __restrict__ alignedT,
                        const float* __restrict__ w1t,
                        const float* __restrict__ b1,
                        float* __restrict__ h1) {
    __shared__ float s_a[32][68];     // [k][px]
    __shared__ float s_b[32][68];     // [k][o]
    int m0  = blockIdx.x * 64;        // pixel base
    int n0  = blockIdx.y * 64;        // out-channel base
    int tid = threadIdx.x;
    int tx  = tid & 15;               // o quad
    int ty  = tid >> 4;               // px quad

    float acc[4][4] = {{0.f}};

    for (int kc = 0; kc < 16; kc++) {
        int c0 = kc * 32;
        const float* asrc;
        int coff;
        if (c0 < 256) { asrc = featT;    coff = c0; }
        else          { asrc = alignedT; coff = c0 - 256; }

        #pragma unroll
        for (int i = tid; i < 512; i += 256) {
            int cq = i & 7, px = i >> 3;
            float4 v = *(const float4*)(asrc + ((size_t)(m0 + px) << 8) + coff + (cq << 2));
            s_a[cq * 4 + 0][px] = v.x;
            s_a[cq * 4 + 1][px] = v.y;
            s_a[cq * 4 + 2][px] = v.z;
            s_a[cq * 4 + 3][px] = v.w;
        }
        #pragma unroll
        for (int i = tid; i < 512; i += 256) {
            int oq = i & 15, cc = i >> 4;
            float4 v = *(const float4*)(w1t + (size_t)(c0 + cc) * 256 + n0 + (oq << 2));
            *(float4*)&s_b[cc][oq << 2] = v;
        }
        __syncthreads();

        #pragma unroll 8
        for (int k = 0; k < 32; k++) {
            float4 av = *(const float4*)&s_a[k][ty << 2];
            float4 bv = *(const float4*)&s_b[k][tx << 2];
            acc[0][0] = fmaf(av.x, bv.x, acc[0][0]);
            acc[0][1] = fmaf(av.x, bv.y, acc[0][1]);
            acc[0][2] = fmaf(av.x, bv.z, acc[0][2]);
            acc[0][3] = fmaf(av.x, bv.w, acc[0][3]);
            acc[1][0] = fmaf(av.y, bv.x, acc[1][0]);
            acc[1][1] = fmaf(av.y, bv.y, acc[1][1]);
            acc[1][2] = fmaf(av.y, bv.z, acc[1][2]);
            acc[1][3] = fmaf(av.y, bv.w, acc[1][3]);
            acc[2][0] = fmaf(av.z, bv.x, acc[2][0]);
            acc[2][1] = fmaf(av.z, bv.y, acc[2][1]);
            acc[2][2] = fmaf(av.z, bv.z, acc[2][2]);
            acc[2][3] = fmaf(av.z, bv.w, acc[2][3]);
            acc[3][0] = fmaf(av.w, bv.x, acc[3][0]);
            acc[3][1] = fmaf(av.w, bv.y, acc[3][1]);
            acc[3][2] = fmaf(av.w, bv.z, acc[3][2]);
            acc[3][3] = fmaf(av.w, bv.w, acc[3][3]);
        }
        __syncthreads();
    }

    float4 bias = *(const float4*)(b1 + n0 + tx * 4);
    #pragma unroll
    for (int i = 0; i < 4; i++) {
        int px = m0 + ty * 4 + i;
        float4 v;
        v.x = acc[i][0] + bias.x;
        v.y = acc[i][1] + bias.y;
        v.z = acc[i][2] + bias.z;
        v.w = acc[i][3] + bias.w;
        *(float4*)(h1 + ((size_t)px << 8) + n0 + tx * 4) = v;
    }
}

// ---------------------------------------------------------------------------
// Conv2: 3x3 pad1, 256 -> 16, FP32, numerics-free.  Verbatim from R12.
// ---------------------------------------------------------------------------
__global__ void k_conv2(const float* __restrict__ h1,
                        const float* __restrict__ w2t,
                        const float* __restrict__ b2,
                        float* __restrict__ h2) {
    __shared__ float s_in[3][18][68];
    int blk = blockIdx.x;          // 0..511
    int b   = blk >> 8;            // 256 blocks per batch
    int r   = blk & 255;
    int y   = r >> 2;
    int w0  = (r & 3) * 16;
    int tid = threadIdx.x;
    int o   = tid & 15;
    int ps  = (tid >> 4) & 7;      // slot 0..7 -> pixels ps, ps+8

    const float* hb = h1 + ((size_t)b << 20);

    float4 a0 = {0.f, 0.f, 0.f, 0.f};
    float4 a1 = {0.f, 0.f, 0.f, 0.f};

    for (int chunk = 0; chunk < 4; chunk++) {
        int c0 = chunk << 6;
        for (int i = tid; i < 3 * 18 * 16; i += 256) {
            int c4 = i & 15;
            int pi = (i >> 4) % 18;
            int ri = (i >> 4) / 18;
            int yy = y + ri - 1;
            int xx = w0 + pi - 1;
            float4 v = {0.f, 0.f, 0.f, 0.f};
            if ((unsigned)yy < 64u && (unsigned)xx < 64u)
                v = *(const float4*)(hb + ((size_t)((yy << 6) | xx) << 8) + c0 + (c4 << 2));
            *(float4*)&s_in[ri][pi][c4 << 2] = v;
        }
        __syncthreads();

        #pragma unroll
        for (int kk = 0; kk < 9; kk++) {
            int ky = kk / 3, kx = kk - ky * 3;
            const float* wp = w2t + (((size_t)(kk * 64 + (c0 >> 2)) * 16 + o) << 2);
            #pragma unroll 8
            for (int c4 = 0; c4 < 16; c4++) {
                float4 wv = *(const float4*)(wp + (c4 << 6));
                float4 i0 = *(const float4*)&s_in[ky][ps + kx][c4 << 2];
                float4 i1 = *(const float4*)&s_in[ky][ps + 8 + kx][c4 << 2];
                a0.x = fmaf(wv.x, i0.x, a0.x);
                a0.y = fmaf(wv.y, i0.y, a0.y);
                a0.z = fmaf(wv.z, i0.z, a0.z);
                a0.w = fmaf(wv.w, i0.w, a0.w);
                a1.x = fmaf(wv.x, i1.x, a1.x);
                a1.y = fmaf(wv.y, i1.y, a1.y);
                a1.z = fmaf(wv.z, i1.z, a1.z);
                a1.w = fmaf(wv.w, i1.w, a1.w);
            }
        }
        __syncthreads();
    }

    size_t bp0 = ((size_t)b << 12) + (y << 6) + w0;
    h2[(bp0 + ps) * 16 + o]     = ((a0.x + a0.y) + (a0.z + a0.w)) + b2[o];
    h2[(bp0 + ps + 8) * 16 + o] = ((a1.x + a1.y) + (a1.z + a1.w)) + b2[o];
}

// ---------------------------------------------------------------------------
// Fused Conv3 (3x3, 16->3) + Conv4 (3x3, 3->2) + softmax -> score.
// Per 16x16 output tile: stage h2 (20x20 halo, channel-major, padded row=21
// -> conflict-free), compute h3 on 18x18 into LDS, then conv4+softmax.
// Bit-equivalent to the separate kernels: OOB taps read staged exact zeros
// (fmaf(w,0,acc)==acc numerically) and image-OOB h3 entries are stored as
// exact 0 to reproduce conv4's tap-skip.  Per-pixel kk-outer/c-inner chain
// order identical to R15's k_conv3/k_score.
// ---------------------------------------------------------------------------
__global__ void k_conv34(const float* __restrict__ h2,
                         const float* __restrict__ w3,
                         const float* __restrict__ b3,
                         const float* __restrict__ w4,
                         const float* __restrict__ b4,
                         float2* __restrict__ score) {
    __shared__ float s_h2[16][20][21];    // channel-major, row padded to 21
    __shared__ float s_h3[3][18][18];
    int x0 = blockIdx.x * 16;
    int y0 = blockIdx.y * 16;
    int b  = blockIdx.z;
    int tid = threadIdx.x;    // 256

    const float* hb = h2 + ((size_t)b << 16);   // b*4096*16

    // stage h2 region [y0-2, y0+18) x [x0-2, x0+18); zeros outside image
    for (int i = tid; i < 20 * 20 * 16; i += 256) {
        int c  = i & 15;
        int pq = i >> 4;              // 0..399
        int rx = pq % 20, ry = pq / 20;
        int yy = y0 + ry - 2, xx = x0 + rx - 2;
        float v = 0.f;
        if ((unsigned)yy < 64u && (unsigned)xx < 64u)
            v = hb[((size_t)((yy << 6) | xx) << 4) + c];
        s_h2[c][ry][rx] = v;
    }
    __syncthreads();

    // conv3 on the 18x18 h3 region (global (y0-1+ry3, x0-1+rx3))
    for (int q = tid; q < 18 * 18; q += 256) {
        int rx3 = q % 18, ry3 = q / 18;
        int yy = y0 + ry3 - 1, xx = x0 + rx3 - 1;
        float a0 = 0.f, a1 = 0.f, a2 = 0.f;
        if ((unsigned)yy < 64u && (unsigned)xx < 64u) {
            #pragma unroll
            for (int kk = 0; kk < 9; kk++) {
                int ky = kk / 3, kx = kk - ky * 3;
                #pragma unroll
                for (int c = 0; c < 16; c++) {
                    float v = s_h2[c][ry3 + ky][rx3 + kx];
                    int wi = c * 9 + kk;
                    a0 = fmaf(w3[wi],       v, a0);
                    a1 = fmaf(w3[144 + wi], v, a1);
                    a2 = fmaf(w3[288 + wi], v, a2);
                }
            }
            a0 += b3[0]; a1 += b3[1]; a2 += b3[2];
        }
        s_h3[0][ry3][rx3] = a0;
        s_h3[1][ry3][rx3] = a1;
        s_h3[2][ry3][rx3] = a2;
    }
    __syncthreads();

    // conv4 + softmax, one thread per output pixel
    int tx = tid & 15, ty = tid >> 4;
    float l0 = 0.f, l1 = 0.f;
    #pragma unroll
    for (int kk = 0; kk < 9; kk++) {
        int ky = kk / 3, kx = kk - ky * 3;
        #pragma unroll
        for (int c = 0; c < 3; c++) {
            float v = s_h3[c][ty + ky][tx + kx];
            int wi = c * 9 + kk;
            l0 = fmaf(w4[wi],      v, l0);
            l1 = fmaf(w4[27 + wi], v, l1);
        }
    }
    l0 += b4[0];
    l1 += b4[1];

    float m  = fmaxf(l0, l1);
    float e0 = expf(l0 - m);
    float e1 = expf(l1 - m);
    float s  = e0 + e1;
    int bp = (b << 12) | ((y0 + ty) << 6) | (x0 + tx);
    score[bp] = make_float2(e0 / s, e1 / s);
}

// ---------------------------------------------------------------------------
// Blend + on-the-fly NHWC->NCHW transpose of aligned.  Verbatim from R11.
// ---------------------------------------------------------------------------
__global__ void k_blend(const float* __restrict__ feat,
                        const float* __restrict__ alignedT,
                        const float2* __restrict__ score,
                        float* __restrict__ out) {
    __shared__ float tile[32][33];
    int b  = blockIdx.z;
    int p0 = blockIdx.x * 32;
    int c0 = blockIdx.y * 32;
    int tx = threadIdx.x;     // 32
    int ty = threadIdx.y;     // 8

    const float* at = alignedT + ((size_t)b << 20);
    #pragma unroll
    for (int i = 0; i < 4; i++) {
        int p = p0 + ty + i * 8;
        tile[ty + i * 8][tx] = at[((size_t)p << 8) + c0 + tx];
    }
    __syncthreads();

    int p = p0 + tx;
    float2 s = score[(b << 12) + p];
    #pragma unroll
    for (int i = 0; i < 4; i++) {
        int c = c0 + ty + i * 8;
        size_t idx = (((size_t)(b * 256 + c)) << 12) + p;
        out[idx] = __fadd_rn(__fmul_rn(s.x, feat[idx]),
                             __fmul_rn(s.y, tile[tx][ty + i * 8]));
    }
}

// ---------------------------------------------------------------------------
extern "C" void kernel_launch(void* const* d_in, const int* in_sizes, int n_in,
                              void* d_out, int out_size, void* d_ws, size_t ws_size,
                              hipStream_t stream) {
    const float* feat     = (const float*)d_in[0];
    const float* feat_ref = (const float*)d_in[1];
    const float* w1 = (const float*)d_in[2];
    const float* b1 = (const float*)d_in[3];
    const float* w2 = (const float*)d_in[4];
    const float* b2 = (const float*)d_in[5];
    const float* w3 = (const float*)d_in[6];
    const float* b3 = (const float*)d_in[7];
    const float* w4 = (const float*)d_in[8];
    const float* b4 = (const float*)d_in[9];
    float* out = (float*)d_out;

    const size_t NCP = (size_t)BATCH * CCH * PIX;   // 2,097,152
    char* wsb = (char*)d_ws;
    float*  featT    = (float*)wsb;   wsb += NCP * 4;               // 8 MB
    float*  refT     = (float*)wsb;   wsb += NCP * 4;               // 8 MB
    float*  alignedT = (float*)wsb;   wsb += NCP * 4;               // 8 MB
    float*  h1       = (float*)wsb;   wsb += NCP * 4;               // 8 MB
    float*  h2       = (float*)wsb;   wsb += (size_t)BP_N * 16 * 4;
    float2* sc       = (float2*)wsb;  wsb += (size_t)BP_N * 8;
    float*  w2t      = (float*)wsb;   wsb += (size_t)16 * 256 * 9 * 4;
    float*  w1t      = (float*)wsb;   wsb += (size_t)512 * 256 * 4;

    dim3 tb(32, 8, 1);
    k_transpose2<<<dim3(PIX / 32, CCH / 32, 4), tb, 0, stream>>>(feat, feat_ref, featT, refT);
    k_wprep<<<272, 256, 0, stream>>>(w1, w1t, w2, w2t);

    k_corr_assemble<<<BP_N, 256, 0, stream>>>(featT, refT, alignedT);
    k_conv1<<<dim3(BP_N / 64, 256 / 64, 1), 256, 0, stream>>>(featT, alignedT, w1t, b1, h1);
    k_conv2<<<BP_N / 16, 256, 0, stream>>>(h1, w2t, b2, h2);
    k_conv34<<<dim3(4, 4, BATCH), 256, 0, stream>>>(h2, w3, b3, w4, b4, sc);
    k_blend<<<dim3(PIX / 32, CCH / 32, BATCH), tb, 0, stream>>>(feat, alignedT, sc, out);
}

// Round 3
// 221.797 us; speedup vs baseline: 1.1554x; 1.1554x over previous
//
#include <hip/hip_runtime.h>
#include <hip/hip_bf16.h>
#include <math.h>

// Problem constants (B=2, C=256, H=W=64, D=4, K=9, K2=81)
#define BATCH 2
#define CCH   256
#define HH    64
#define WW    64
#define PIX   (HH*WW)          // 4096
#define K2    81
#define BP_N  (BATCH*PIX)      // 8192

// ---------------------------------------------------------------------------
// NCHW -> NHWC tiled transpose, both feature tensors in one launch.
// z = 0,1 -> feat batches; z = 2,3 -> feat_ref batches.
// ---------------------------------------------------------------------------
__global__ void k_transpose2(const float* __restrict__ feat,
                             const float* __restrict__ feat_ref,
                             float* __restrict__ featT,
                             float* __restrict__ refT) {
    __shared__ float tile[32][33];
    int z  = blockIdx.z;
    int b  = z & 1;
    const float* in  = (z >> 1) ? feat_ref : feat;
    float*       out = (z >> 1) ? refT     : featT;
    int p0 = blockIdx.x * 32;
    int c0 = blockIdx.y * 32;
    int tx = threadIdx.x;     // 32
    int ty = threadIdx.y;     // 8
    const float* ib = in  + (size_t)b * CCH * PIX;
    float*       ob = out + (size_t)b * CCH * PIX;
    #pragma unroll
    for (int i = 0; i < 4; i++) {
        int c = c0 + ty + i * 8;
        int p = p0 + tx;
        tile[ty + i * 8][tx] = ib[(size_t)c * PIX + p];
    }
    __syncthreads();
    #pragma unroll
    for (int i = 0; i < 4; i++) {
        int p = p0 + ty + i * 8;
        int c = c0 + tx;
        ob[(size_t)p * CCH + c] = tile[tx][ty + i * 8];
    }
}

// ---------------------------------------------------------------------------
// Weight prep, one launch: blocks 0..127 -> w1t transpose, 128..271 -> w2t.
// ---------------------------------------------------------------------------
__global__ void k_wprep(const float* __restrict__ w1, float* __restrict__ w1t,
                        const float* __restrict__ w2, float* __restrict__ w2t) {
    __shared__ float tile[32][33];
    int blk = blockIdx.x;
    int tid = threadIdx.x;            // 256 flat
    if (blk < 128) {
        int c0 = (blk & 15) * 32;
        int o0 = (blk >> 4) * 32;
        int tx = tid & 31;
        int ty = tid >> 5;
        #pragma unroll
        for (int i = 0; i < 4; i++)
            tile[ty + i * 8][tx] = w1[(size_t)(o0 + ty + i * 8) * 512 + c0 + tx];
        __syncthreads();
        #pragma unroll
        for (int i = 0; i < 4; i++)
            w1t[(size_t)(c0 + ty + i * 8) * 256 + o0 + tx] = tile[tx][ty + i * 8];
    } else {
        int i = (blk - 128) * 256 + tid;
        if (i < 16 * 256 * 9) {
            int o  = i / 2304;
            int r  = i % 2304;        // c*9 + kk
            int c  = r / 9;
            int kk = r % 9;
            int cg = c >> 2, ci = c & 3;
            w2t[(((kk * 64 + cg) * 16 + o) << 2) + ci] = w2[i];
        }
    }
}

// ---------------------------------------------------------------------------
// Correlation + sum-normalize + assemble, PPB=2 (pixel pair per block).
// BIT-EXACT recipe preserved per (pixel,k):
//   phase 1: per-k t=0..7 ascending fmaf chain, butterfly xor 8,16,4,2,1
//   phase 2: sequential ascending-k fp32 add chain over ALL 81 (zeros incl.)
//   phase 3: sequential ascending-k fmaf chain; boundary union entries carry
//            coefficient exactly +0.0f -> fmaf(+0,v,acc) is an identity for
//            finite data (any ±0 divergence is invisible to absmax).
//
// R17: two adjacent pixels (w, w+1) share a 9x10 union ref window (90 px vs
// 2x81=162) -> phase-1 and phase-3 ref loads drop 44%.  Each union ref slice
// is loaded once and feeds BOTH pixels' chains (each chain keeps its own
// exact FP order: p0's k=(uy,ux), p1's k=(uy,ux-1)).  Setup/compaction/
// barriers amortized 2x.  XCD swizzle retained (512-pair bands).
// ---------------------------------------------------------------------------
__global__ void k_corr_assemble(const float* __restrict__ featT,
                                const float* __restrict__ refT,
                                float* __restrict__ alignedT) {
    int blk = blockIdx.x;                        // 0..4095
    int pr  = ((blk & 7) << 9) | (blk >> 3);     // XCD-contiguous pair bands
    int bp  = pr << 1;                           // even pixel of the pair
    int b  = bp >> 12;
    int p  = bp & 4095;
    int h  = p >> 6, w = p & 63;                 // w is even
    int tid = threadIdx.x;                       // 0..255

    __shared__ float s_aff0[K2];
    __shared__ float s_aff1[K2];
    __shared__ __align__(8) int2 s_u[96];        // compacted (poff, meta)
    __shared__ int   s_hi_a[32];
    __shared__ int   s_hi_b[32];
    __shared__ int   s_cnt0, s_cnt1;
    __shared__ float s_den0, s_den1;
    __shared__ __align__(16) float s_c0[96];     // p0 coeffs along union list
    __shared__ __align__(16) float s_c1[96];     // p1 coeffs
    __shared__ __align__(16) int   s_po[96];     // byte offsets

    int hw = tid >> 5;        // 0..7
    int j  = tid & 31;        // 0..31

    // feat fragments for both pixels in registers
    const float* fb = featT + ((size_t)bp << 8) + j;
    float f0[8], f1[8];
    #pragma unroll
    for (int t = 0; t < 8; t++) { f0[t] = fb[32 * t]; f1[t] = fb[256 + 32 * t]; }

    if (tid < K2) { s_aff0[tid] = 0.f; s_aff1[tid] = 0.f; }

    // --- compacted union list (90 candidates), order-preserving ---
    // u = uy*10+ux, ref pixel (h+uy-4, w+ux-4).  meta = (ux<<8) | (uy*9+ux).
    if (tid < 128) {
        int u  = tid;
        int uy = u / 10, ux = u - uy * 10;
        int y  = h + uy - 4, x = w + ux - 4;
        bool valid = (u < 90) && ((unsigned)y < 64u) && ((unsigned)x < 64u);
        int poff = ((y << 6) | x) << 10;          // pix*256*4 bytes
        int meta = (ux << 8) | (uy * 9 + ux);
        unsigned long long m = __ballot(valid);
        int lane   = tid & 63;
        int prefix = __popcll(m & ((1ULL << lane) - 1ULL));
        if (tid < 64) {
            if (valid) s_u[prefix] = make_int2(poff, meta);
            if (tid == 0) s_cnt0 = (int)__popcll(m);
        } else {
            if (valid) { s_hi_a[prefix] = poff; s_hi_b[prefix] = meta; }
            if (tid == 64) s_cnt1 = (int)__popcll(m);
        }
    }
    __syncthreads();
    int n0 = s_cnt0, n1 = s_cnt1;
    int nu = n0 + n1;                  // uniform across block (30..90)
    if (tid < n1) s_u[n0 + tid] = make_int2(s_hi_a[tid], s_hi_b[tid]);
    __syncthreads();

    const float* rb  = refT + ((size_t)b << 20);   // b*4096*256
    const char*  rbj = (const char*)rb + 4 * j;

    // Phase 1: 2 union pixels per group-iteration; each loaded slice feeds
    // both pixels' chains.  Per-(pixel,k) FP sequence unchanged.
    for (int ii = 2 * hw; ii < nu; ii += 16) {
        int2 U0 = s_u[ii];
        bool has1 = (ii + 1) < nu;
        int2 U1 = has1 ? s_u[ii + 1] : U0;
        const char* rp0 = rbj + U0.x;
        const char* rp1 = rbj + U1.x;
        float r0[8], r1[8];
        #pragma unroll
        for (int t = 0; t < 8; t++) {
            r0[t] = *(const float*)(rp0 + 128 * t);
            r1[t] = *(const float*)(rp1 + 128 * t);
        }
        float pa0 = 0.f, pb0 = 0.f, pa1 = 0.f, pb1 = 0.f;
        #pragma unroll
        for (int t = 0; t < 8; t++) {
            pa0 = fmaf(f0[t], r0[t], pa0);
            pb0 = fmaf(f1[t], r0[t], pb0);
            pa1 = fmaf(f0[t], r1[t], pa1);
            pb1 = fmaf(f1[t], r1[t], pb1);
        }
        pa0 = __fadd_rn(pa0, __shfl_xor(pa0, 8));
        pb0 = __fadd_rn(pb0, __shfl_xor(pb0, 8));
        pa1 = __fadd_rn(pa1, __shfl_xor(pa1, 8));
        pb1 = __fadd_rn(pb1, __shfl_xor(pb1, 8));
        pa0 = __fadd_rn(pa0, __shfl_xor(pa0, 16));
        pb0 = __fadd_rn(pb0, __shfl_xor(pb0, 16));
        pa1 = __fadd_rn(pa1, __shfl_xor(pa1, 16));
        pb1 = __fadd_rn(pb1, __shfl_xor(pb1, 16));
        pa0 = __fadd_rn(pa0, __shfl_xor(pa0, 4));
        pb0 = __fadd_rn(pb0, __shfl_xor(pb0, 4));
        pa1 = __fadd_rn(pa1, __shfl_xor(pa1, 4));
        pb1 = __fadd_rn(pb1, __shfl_xor(pb1, 4));
        pa0 = __fadd_rn(pa0, __shfl_xor(pa0, 2));
        pb0 = __fadd_rn(pb0, __shfl_xor(pb0, 2));
        pa1 = __fadd_rn(pa1, __shfl_xor(pa1, 2));
        pb1 = __fadd_rn(pb1, __shfl_xor(pb1, 2));
        pa0 = __fadd_rn(pa0, __shfl_xor(pa0, 1));
        pb0 = __fadd_rn(pb0, __shfl_xor(pb0, 1));
        pa1 = __fadd_rn(pa1, __shfl_xor(pa1, 1));
        pb1 = __fadd_rn(pb1, __shfl_xor(pb1, 1));
        if (j == 0) {
            int k0 = U0.y & 255, ux0 = U0.y >> 8;
            if (ux0 < 9) s_aff0[k0] = pa0;       // p0's k = (uy,ux)
            if (ux0 > 0) s_aff1[k0 - 1] = pb0;   // p1's k = (uy,ux-1)
            if (has1) {
                int k1 = U1.y & 255, ux1 = U1.y >> 8;
                if (ux1 < 9) s_aff0[k1] = pa1;
                if (ux1 > 0) s_aff1[k1 - 1] = pb1;
            }
        }
    }
    __syncthreads();

    // Phase 2: sequential ascending-k fp32 add chain over ALL 81, per pixel.
    if (tid < 2) {
        const float* sa = tid ? s_aff1 : s_aff0;
        float s = 0.f;
        for (int k = 0; k < K2; k++) s = __fadd_rn(s, sa[k]);
        float d = __fadd_rn(s, 1e-7f);
        if (tid) s_den1 = d; else s_den0 = d;
    }
    __syncthreads();

    // Per-union coefficients (one division per valid (pixel,k), as before;
    // boundary entries get exact +0.0f).
    if (tid < nu) {
        int2 uu = s_u[tid];
        int k0 = uu.y & 255, ux = uu.y >> 8;
        s_po[tid] = uu.x;
        s_c0[tid] = (ux < 9) ? __fdiv_rn(s_aff0[k0], s_den0) : 0.f;
        s_c1[tid] = (ux > 0) ? __fdiv_rn(s_aff1[k0 - 1], s_den1) : 0.f;
    }
    __syncthreads();

    // Phase 3: ascending union list = ascending k per pixel; each loaded
    // value feeds both pixels' FMA chains.  8-deep load batches.
    const char* rbc = (const char*)rb + ((size_t)tid << 2);
    float a0 = 0.f, a1 = 0.f;
    int i = 0;
    for (; i + 8 <= nu; i += 8) {
        float4 cA0 = *(const float4*)&s_c0[i];
        float4 cA1 = *(const float4*)&s_c0[i + 4];
        float4 cB0 = *(const float4*)&s_c1[i];
        float4 cB1 = *(const float4*)&s_c1[i + 4];
        int4   poA = *(const int4*)&s_po[i];
        int4   poB = *(const int4*)&s_po[i + 4];
        float v0 = *(const float*)(rbc + poA.x);
        float v1 = *(const float*)(rbc + poA.y);
        float v2 = *(const float*)(rbc + poA.z);
        float v3 = *(const float*)(rbc + poA.w);
        float v4 = *(const float*)(rbc + poB.x);
        float v5 = *(const float*)(rbc + poB.y);
        float v6 = *(const float*)(rbc + poB.z);
        float v7 = *(const float*)(rbc + poB.w);
        a0 = fmaf(cA0.x, v0, a0);  a1 = fmaf(cB0.x, v0, a1);
        a0 = fmaf(cA0.y, v1, a0);  a1 = fmaf(cB0.y, v1, a1);
        a0 = fmaf(cA0.z, v2, a0);  a1 = fmaf(cB0.z, v2, a1);
        a0 = fmaf(cA0.w, v3, a0);  a1 = fmaf(cB0.w, v3, a1);
        a0 = fmaf(cA1.x, v4, a0);  a1 = fmaf(cB1.x, v4, a1);
        a0 = fmaf(cA1.y, v5, a0);  a1 = fmaf(cB1.y, v5, a1);
        a0 = fmaf(cA1.z, v6, a0);  a1 = fmaf(cB1.z, v6, a1);
        a0 = fmaf(cA1.w, v7, a0);  a1 = fmaf(cB1.w, v7, a1);
    }
    if (i + 4 <= nu) {
        float4 cA = *(const float4*)&s_c0[i];
        float4 cB = *(const float4*)&s_c1[i];
        int4   po = *(const int4*)&s_po[i];
        float v0 = *(const float*)(rbc + po.x);
        float v1 = *(const float*)(rbc + po.y);
        float v2 = *(const float*)(rbc + po.z);
        float v3 = *(const float*)(rbc + po.w);
        a0 = fmaf(cA.x, v0, a0);  a1 = fmaf(cB.x, v0, a1);
        a0 = fmaf(cA.y, v1, a0);  a1 = fmaf(cB.y, v1, a1);
        a0 = fmaf(cA.z, v2, a0);  a1 = fmaf(cB.z, v2, a1);
        a0 = fmaf(cA.w, v3, a0);  a1 = fmaf(cB.w, v3, a1);
        i += 4;
    }
    for (; i < nu; i++) {
        float v = *(const float*)(rbc + s_po[i]);
        a0 = fmaf(s_c0[i], v, a0);
        a1 = fmaf(s_c1[i], v, a1);
    }
    alignedT[((size_t)bp << 8) + tid]       = a0;
    alignedT[((size_t)(bp + 1) << 8) + tid] = a1;
}

// ---------------------------------------------------------------------------
// Conv1: 1x1, 512 -> 256, FP32 GEMM (numerics-free).  Verbatim from R13.
// ---------------------------------------------------------------------------
__global__ void k_conv1(const float* __restrict__ featT,
                        const float* __restrict__ alignedT,
                        const float* __restrict__ w1t,
                        const float* __restrict__ b1,
                        float* __restrict__ h1) {
    __shared__ float s_a[32][68];     // [k][px]
    __shared__ float s_b[32][68];     // [k][o]
    int m0  = blockIdx.x * 64;        // pixel base
    int n0  = blockIdx.y * 64;        // out-channel base
    int tid = threadIdx.x;
    int tx  = tid & 15;               // o quad
    int ty  = tid >> 4;               // px quad

    float acc[4][4] = {{0.f}};

    for (int kc = 0; kc < 16; kc++) {
        int c0 = kc * 32;
        const float* asrc;
        int coff;
        if (c0 < 256) { asrc = featT;    coff = c0; }
        else          { asrc = alignedT; coff = c0 - 256; }

        #pragma unroll
        for (int i = tid; i < 512; i += 256) {
            int cq = i & 7, px = i >> 3;
            float4 v = *(const float4*)(asrc + ((size_t)(m0 + px) << 8) + coff + (cq << 2));
            s_a[cq * 4 + 0][px] = v.x;
            s_a[cq * 4 + 1][px] = v.y;
            s_a[cq * 4 + 2][px] = v.z;
            s_a[cq * 4 + 3][px] = v.w;
        }
        #pragma unroll
        for (int i = tid; i < 512; i += 256) {
            int oq = i & 15, cc = i >> 4;
            float4 v = *(const float4*)(w1t + (size_t)(c0 + cc) * 256 + n0 + (oq << 2));
            *(float4*)&s_b[cc][oq << 2] = v;
        }
        __syncthreads();

        #pragma unroll 8
        for (int k = 0; k < 32; k++) {
            float4 av = *(const float4*)&s_a[k][ty << 2];
            float4 bv = *(const float4*)&s_b[k][tx << 2];
            acc[0][0] = fmaf(av.x, bv.x, acc[0][0]);
            acc[0][1] = fmaf(av.x, bv.y, acc[0][1]);
            acc[0][2] = fmaf(av.x, bv.z, acc[0][2]);
            acc[0][3] = fmaf(av.x, bv.w, acc[0][3]);
            acc[1][0] = fmaf(av.y, bv.x, acc[1][0]);
            acc[1][1] = fmaf(av.y, bv.y, acc[1][1]);
            acc[1][2] = fmaf(av.y, bv.z, acc[1][2]);
            acc[1][3] = fmaf(av.y, bv.w, acc[1][3]);
            acc[2][0] = fmaf(av.z, bv.x, acc[2][0]);
            acc[2][1] = fmaf(av.z, bv.y, acc[2][1]);
            acc[2][2] = fmaf(av.z, bv.z, acc[2][2]);
            acc[2][3] = fmaf(av.z, bv.w, acc[2][3]);
            acc[3][0] = fmaf(av.w, bv.x, acc[3][0]);
            acc[3][1] = fmaf(av.w, bv.y, acc[3][1]);
            acc[3][2] = fmaf(av.w, bv.z, acc[3][2]);
            acc[3][3] = fmaf(av.w, bv.w, acc[3][3]);
        }
        __syncthreads();
    }

    float4 bias = *(const float4*)(b1 + n0 + tx * 4);
    #pragma unroll
    for (int i = 0; i < 4; i++) {
        int px = m0 + ty * 4 + i;
        float4 v;
        v.x = acc[i][0] + bias.x;
        v.y = acc[i][1] + bias.y;
        v.z = acc[i][2] + bias.z;
        v.w = acc[i][3] + bias.w;
        *(float4*)(h1 + ((size_t)px << 8) + n0 + tx * 4) = v;
    }
}

// ---------------------------------------------------------------------------
// Conv2: 3x3 pad1, 256 -> 16, FP32, numerics-free.  Verbatim from R12.
// ---------------------------------------------------------------------------
__global__ void k_conv2(const float* __restrict__ h1,
                        const float* __restrict__ w2t,
                        const float* __restrict__ b2,
                        float* __restrict__ h2) {
    __shared__ float s_in[3][18][68];
    int blk = blockIdx.x;          // 0..511
    int b   = blk >> 8;            // 256 blocks per batch
    int r   = blk & 255;
    int y   = r >> 2;
    int w0  = (r & 3) * 16;
    int tid = threadIdx.x;
    int o   = tid & 15;
    int ps  = (tid >> 4) & 7;      // slot 0..7 -> pixels ps, ps+8

    const float* hb = h1 + ((size_t)b << 20);

    float4 a0 = {0.f, 0.f, 0.f, 0.f};
    float4 a1 = {0.f, 0.f, 0.f, 0.f};

    for (int chunk = 0; chunk < 4; chunk++) {
        int c0 = chunk << 6;
        for (int i = tid; i < 3 * 18 * 16; i += 256) {
            int c4 = i & 15;
            int pi = (i >> 4) % 18;
            int ri = (i >> 4) / 18;
            int yy = y + ri - 1;
            int xx = w0 + pi - 1;
            float4 v = {0.f, 0.f, 0.f, 0.f};
            if ((unsigned)yy < 64u && (unsigned)xx < 64u)
                v = *(const float4*)(hb + ((size_t)((yy << 6) | xx) << 8) + c0 + (c4 << 2));
            *(float4*)&s_in[ri][pi][c4 << 2] = v;
        }
        __syncthreads();

        #pragma unroll
        for (int kk = 0; kk < 9; kk++) {
            int ky = kk / 3, kx = kk - ky * 3;
            const float* wp = w2t + (((size_t)(kk * 64 + (c0 >> 2)) * 16 + o) << 2);
            #pragma unroll 8
            for (int c4 = 0; c4 < 16; c4++) {
                float4 wv = *(const float4*)(wp + (c4 << 6));
                float4 i0 = *(const float4*)&s_in[ky][ps + kx][c4 << 2];
                float4 i1 = *(const float4*)&s_in[ky][ps + 8 + kx][c4 << 2];
                a0.x = fmaf(wv.x, i0.x, a0.x);
                a0.y = fmaf(wv.y, i0.y, a0.y);
                a0.z = fmaf(wv.z, i0.z, a0.z);
                a0.w = fmaf(wv.w, i0.w, a0.w);
                a1.x = fmaf(wv.x, i1.x, a1.x);
                a1.y = fmaf(wv.y, i1.y, a1.y);
                a1.z = fmaf(wv.z, i1.z, a1.z);
                a1.w = fmaf(wv.w, i1.w, a1.w);
            }
        }
        __syncthreads();
    }

    size_t bp0 = ((size_t)b << 12) + (y << 6) + w0;
    h2[(bp0 + ps) * 16 + o]     = ((a0.x + a0.y) + (a0.z + a0.w)) + b2[o];
    h2[(bp0 + ps + 8) * 16 + o] = ((a1.x + a1.y) + (a1.z + a1.w)) + b2[o];
}

// ---------------------------------------------------------------------------
// Conv3: 3x3 pad1, 16 -> 3, FP32, numerics-free.  Thread per pixel.
// (R15 verbatim — R16's fused conv34 regressed; reverted.)
// ---------------------------------------------------------------------------
__global__ void k_conv3(const float* __restrict__ h2,
                        const float* __restrict__ w3,
                        const float* __restrict__ b3,
                        float* __restrict__ h3) {
    int bp = blockIdx.x * 256 + threadIdx.x;
    if (bp >= BP_N) return;
    int b = bp >> 12;
    int p = bp & 4095;
    int h = p >> 6, w = p & 63;
    const float* hb = h2 + ((size_t)b << 16);   // b*4096*16

    float a0 = 0.f, a1 = 0.f, a2 = 0.f;
    #pragma unroll
    for (int kk = 0; kk < 9; kk++) {
        int ky = kk / 3, kx = kk - ky * 3;
        int y = h + ky - 1, x = w + kx - 1;
        if ((unsigned)y >= 64u || (unsigned)x >= 64u) continue;
        const float* ip = hb + (size_t)((y << 6) | x) * 16;
        #pragma unroll
        for (int c = 0; c < 16; c++) {
            float v = ip[c];
            int wi = c * 9 + kk;
            a0 = fmaf(w3[wi],       v, a0);
            a1 = fmaf(w3[144 + wi], v, a1);
            a2 = fmaf(w3[288 + wi], v, a2);
        }
    }
    h3[(size_t)bp * 3 + 0] = a0 + b3[0];
    h3[(size_t)bp * 3 + 1] = a1 + b3[1];
    h3[(size_t)bp * 3 + 2] = a2 + b3[2];
}

// ---------------------------------------------------------------------------
// Conv4 (3x3, 3 -> 2) + softmax -> (score0, score1), FP32, numerics-free.
// (R15 verbatim.)
// ---------------------------------------------------------------------------
__global__ void k_score(const float* __restrict__ h3,
                        const float* __restrict__ w4,
                        const float* __restrict__ b4,
                        float2* __restrict__ score) {
    int bp = blockIdx.x * 256 + threadIdx.x;
    if (bp >= BP_N) return;
    int b = bp >> 12;
    int p = bp & 4095;
    int h = p >> 6, w = p & 63;
    const float* hb = h3 + (size_t)b * PIX * 3;

    float l0 = 0.f, l1 = 0.f;
    #pragma unroll
    for (int kk = 0; kk < 9; kk++) {
        int ky = kk / 3, kx = kk - ky * 3;
        int y = h + ky - 1, x = w + kx - 1;
        if ((unsigned)y >= 64u || (unsigned)x >= 64u) continue;
        const float* ip = hb + (size_t)((y << 6) | x) * 3;
        #pragma unroll
        for (int c = 0; c < 3; c++) {
            float v = ip[c];
            int wi = c * 9 + kk;
            l0 = fmaf(w4[wi],      v, l0);
            l1 = fmaf(w4[27 + wi], v, l1);
        }
    }
    l0 += b4[0];
    l1 += b4[1];

    float m  = fmaxf(l0, l1);
    float e0 = expf(l0 - m);
    float e1 = expf(l1 - m);
    float s  = e0 + e1;
    score[bp] = make_float2(e0 / s, e1 / s);
}

// ---------------------------------------------------------------------------
// Blend + on-the-fly NHWC->NCHW transpose of aligned.  Verbatim from R11.
// ---------------------------------------------------------------------------
__global__ void k_blend(const float* __restrict__ feat,
                        const float* __restrict__ alignedT,
                        const float2* __restrict__ score,
                        float* __restrict__ out) {
    __shared__ float tile[32][33];
    int b  = blockIdx.z;
    int p0 = blockIdx.x * 32;
    int c0 = blockIdx.y * 32;
    int tx = threadIdx.x;     // 32
    int ty = threadIdx.y;     // 8

    const float* at = alignedT + ((size_t)b << 20);
    #pragma unroll
    for (int i = 0; i < 4; i++) {
        int p = p0 + ty + i * 8;
        tile[ty + i * 8][tx] = at[((size_t)p << 8) + c0 + tx];
    }
    __syncthreads();

    int p = p0 + tx;
    float2 s = score[(b << 12) + p];
    #pragma unroll
    for (int i = 0; i < 4; i++) {
        int c = c0 + ty + i * 8;
        size_t idx = (((size_t)(b * 256 + c)) << 12) + p;
        out[idx] = __fadd_rn(__fmul_rn(s.x, feat[idx]),
                             __fmul_rn(s.y, tile[tx][ty + i * 8]));
    }
}

// ---------------------------------------------------------------------------
extern "C" void kernel_launch(void* const* d_in, const int* in_sizes, int n_in,
                              void* d_out, int out_size, void* d_ws, size_t ws_size,
                              hipStream_t stream) {
    const float* feat     = (const float*)d_in[0];
    const float* feat_ref = (const float*)d_in[1];
    const float* w1 = (const float*)d_in[2];
    const float* b1 = (const float*)d_in[3];
    const float* w2 = (const float*)d_in[4];
    const float* b2 = (const float*)d_in[5];
    const float* w3 = (const float*)d_in[6];
    const float* b3 = (const float*)d_in[7];
    const float* w4 = (const float*)d_in[8];
    const float* b4 = (const float*)d_in[9];
    float* out = (float*)d_out;

    const size_t NCP = (size_t)BATCH * CCH * PIX;   // 2,097,152
    char* wsb = (char*)d_ws;
    float*  featT    = (float*)wsb;   wsb += NCP * 4;               // 8 MB
    float*  refT     = (float*)wsb;   wsb += NCP * 4;               // 8 MB
    float*  alignedT = (float*)wsb;   wsb += NCP * 4;               // 8 MB
    float*  h1       = (float*)wsb;   wsb += NCP * 4;               // 8 MB
    float*  h2       = (float*)wsb;   wsb += (size_t)BP_N * 16 * 4;
    float*  h3       = (float*)wsb;   wsb += (size_t)BP_N * 3 * 4;
    float2* sc       = (float2*)wsb;  wsb += (size_t)BP_N * 8;
    float*  w2t      = (float*)wsb;   wsb += (size_t)16 * 256 * 9 * 4;
    float*  w1t      = (float*)wsb;   wsb += (size_t)512 * 256 * 4;

    dim3 tb(32, 8, 1);
    k_transpose2<<<dim3(PIX / 32, CCH / 32, 4), tb, 0, stream>>>(feat, feat_ref, featT, refT);
    k_wprep<<<272, 256, 0, stream>>>(w1, w1t, w2, w2t);

    k_corr_assemble<<<BP_N / 2, 256, 0, stream>>>(featT, refT, alignedT);
    k_conv1<<<dim3(BP_N / 64, 256 / 64, 1), 256, 0, stream>>>(featT, alignedT, w1t, b1, h1);
    k_conv2<<<BP_N / 16, 256, 0, stream>>>(h1, w2t, b2, h2);
    k_conv3<<<BP_N / 256, 256, 0, stream>>>(h2, w3, b3, h3);
    k_score<<<BP_N / 256, 256, 0, stream>>>(h3, w4, b4, sc);
    k_blend<<<dim3(PIX / 32, CCH / 32, BATCH), tb, 0, stream>>>(feat, alignedT, sc, out);
}

// Round 4
// 216.483 us; speedup vs baseline: 1.1838x; 1.0245x over previous
//
#include <hip/hip_runtime.h>
#include <hip/hip_bf16.h>
#include <math.h>

// Problem constants (B=2, C=256, H=W=64, D=4, K=9, K2=81)
#define BATCH 2
#define CCH   256
#define HH    64
#define WW    64
#define PIX   (HH*WW)          // 4096
#define K2    81
#define BP_N  (BATCH*PIX)      // 8192

// ---------------------------------------------------------------------------
// NCHW -> NHWC tiled transpose, both feature tensors in one launch.
// z = 0,1 -> feat batches; z = 2,3 -> feat_ref batches.
// ---------------------------------------------------------------------------
__global__ void k_transpose2(const float* __restrict__ feat,
                             const float* __restrict__ feat_ref,
                             float* __restrict__ featT,
                             float* __restrict__ refT) {
    __shared__ float tile[32][33];
    int z  = blockIdx.z;
    int b  = z & 1;
    const float* in  = (z >> 1) ? feat_ref : feat;
    float*       out = (z >> 1) ? refT     : featT;
    int p0 = blockIdx.x * 32;
    int c0 = blockIdx.y * 32;
    int tx = threadIdx.x;     // 32
    int ty = threadIdx.y;     // 8
    const float* ib = in  + (size_t)b * CCH * PIX;
    float*       ob = out + (size_t)b * CCH * PIX;
    #pragma unroll
    for (int i = 0; i < 4; i++) {
        int c = c0 + ty + i * 8;
        int p = p0 + tx;
        tile[ty + i * 8][tx] = ib[(size_t)c * PIX + p];
    }
    __syncthreads();
    #pragma unroll
    for (int i = 0; i < 4; i++) {
        int p = p0 + ty + i * 8;
        int c = c0 + tx;
        ob[(size_t)p * CCH + c] = tile[tx][ty + i * 8];
    }
}

// ---------------------------------------------------------------------------
// Weight prep, one launch: blocks 0..127 -> w1t transpose, 128..271 -> w2t.
// ---------------------------------------------------------------------------
__global__ void k_wprep(const float* __restrict__ w1, float* __restrict__ w1t,
                        const float* __restrict__ w2, float* __restrict__ w2t) {
    __shared__ float tile[32][33];
    int blk = blockIdx.x;
    int tid = threadIdx.x;            // 256 flat
    if (blk < 128) {
        int c0 = (blk & 15) * 32;
        int o0 = (blk >> 4) * 32;
        int tx = tid & 31;
        int ty = tid >> 5;
        #pragma unroll
        for (int i = 0; i < 4; i++)
            tile[ty + i * 8][tx] = w1[(size_t)(o0 + ty + i * 8) * 512 + c0 + tx];
        __syncthreads();
        #pragma unroll
        for (int i = 0; i < 4; i++)
            w1t[(size_t)(c0 + ty + i * 8) * 256 + o0 + tx] = tile[tx][ty + i * 8];
    } else {
        int i = (blk - 128) * 256 + tid;
        if (i < 16 * 256 * 9) {
            int o  = i / 2304;
            int r  = i % 2304;        // c*9 + kk
            int c  = r / 9;
            int kk = r % 9;
            int cg = c >> 2, ci = c & 3;
            w2t[(((kk * 64 + cg) * 16 + o) << 2) + ci] = w2[i];
        }
    }
}

// ---------------------------------------------------------------------------
// Correlation + sum-normalize + assemble, PPB=2 (pixel pair per block).
// BIT-EXACT recipe preserved per (pixel,k):
//   phase 1: per-k t=0..7 ascending fmaf chain, butterfly xor 8,16,4,2,1
//   phase 2: sequential ascending-k fp32 add chain over ALL 81 (zeros incl.)
//   phase 3: sequential ascending-k fmaf chain; boundary union entries carry
//            coefficient exactly +0.0f (fmaf(+0,v,acc) identity).
//
// R18: phase-1 SOFTWARE PIPELINE only — no rounding change.  R17's counters
// (VALUBusy 46%, occ 47%, L2 BW 13.5/34.5 TB/s) showed stall-bound on the
// serial chain {global loads ~200cy -> FMA -> 5 dependent shuffles}.  Now the
// NEXT iteration's s_u read + 16 ref loads issue between the current FMA
// chain and the current shuffle chain, so load latency hides under the
// shuffle chain.  Per-(pixel,k) FP sequence and write order unchanged.
// ---------------------------------------------------------------------------
__global__ void k_corr_assemble(const float* __restrict__ featT,
                                const float* __restrict__ refT,
                                float* __restrict__ alignedT) {
    int blk = blockIdx.x;                        // 0..4095
    int pr  = ((blk & 7) << 9) | (blk >> 3);     // XCD-contiguous pair bands
    int bp  = pr << 1;                           // even pixel of the pair
    int b  = bp >> 12;
    int p  = bp & 4095;
    int h  = p >> 6, w = p & 63;                 // w is even
    int tid = threadIdx.x;                       // 0..255

    __shared__ float s_aff0[K2];
    __shared__ float s_aff1[K2];
    __shared__ __align__(8) int2 s_u[96];        // compacted (poff, meta)
    __shared__ int   s_hi_a[32];
    __shared__ int   s_hi_b[32];
    __shared__ int   s_cnt0, s_cnt1;
    __shared__ float s_den0, s_den1;
    __shared__ __align__(16) float s_c0[96];     // p0 coeffs along union list
    __shared__ __align__(16) float s_c1[96];     // p1 coeffs
    __shared__ __align__(16) int   s_po[96];     // byte offsets

    int hw = tid >> 5;        // 0..7
    int j  = tid & 31;        // 0..31

    // feat fragments for both pixels in registers
    const float* fb = featT + ((size_t)bp << 8) + j;
    float f0[8], f1[8];
    #pragma unroll
    for (int t = 0; t < 8; t++) { f0[t] = fb[32 * t]; f1[t] = fb[256 + 32 * t]; }

    if (tid < K2) { s_aff0[tid] = 0.f; s_aff1[tid] = 0.f; }

    // --- compacted union list (90 candidates), order-preserving ---
    // u = uy*10+ux, ref pixel (h+uy-4, w+ux-4).  meta = (ux<<8) | (uy*9+ux).
    if (tid < 128) {
        int u  = tid;
        int uy = u / 10, ux = u - uy * 10;
        int y  = h + uy - 4, x = w + ux - 4;
        bool valid = (u < 90) && ((unsigned)y < 64u) && ((unsigned)x < 64u);
        int poff = ((y << 6) | x) << 10;          // pix*256*4 bytes
        int meta = (ux << 8) | (uy * 9 + ux);
        unsigned long long m = __ballot(valid);
        int lane   = tid & 63;
        int prefix = __popcll(m & ((1ULL << lane) - 1ULL));
        if (tid < 64) {
            if (valid) s_u[prefix] = make_int2(poff, meta);
            if (tid == 0) s_cnt0 = (int)__popcll(m);
        } else {
            if (valid) { s_hi_a[prefix] = poff; s_hi_b[prefix] = meta; }
            if (tid == 64) s_cnt1 = (int)__popcll(m);
        }
    }
    __syncthreads();
    int n0 = s_cnt0, n1 = s_cnt1;
    int nu = n0 + n1;                  // uniform across block (30..90)
    if (tid < n1) s_u[n0 + tid] = make_int2(s_hi_a[tid], s_hi_b[tid]);
    __syncthreads();

    const float* rb  = refT + ((size_t)b << 20);   // b*4096*256
    const char*  rbj = (const char*)rb + 4 * j;

    // Phase 1 (pipelined): prefetch next (U,ref-slice) before the shuffle
    // chain of the current iteration.  FP sequence per (pixel,k) unchanged.
    int ii = 2 * hw;
    bool act = ii < nu;
    int2 U0 = make_int2(0, 0), U1 = make_int2(0, 0);
    bool has1 = false;
    float r0[8], r1[8];
    if (act) {
        U0 = s_u[ii];
        has1 = (ii + 1) < nu;
        U1 = has1 ? s_u[ii + 1] : U0;
        const char* rp0 = rbj + U0.x;
        const char* rp1 = rbj + U1.x;
        #pragma unroll
        for (int t = 0; t < 8; t++) {
            r0[t] = *(const float*)(rp0 + 128 * t);
            r1[t] = *(const float*)(rp1 + 128 * t);
        }
    }
    while (act) {
        // consume current ref slices (exact per-k ascending-t chains)
        float pa0 = 0.f, pb0 = 0.f, pa1 = 0.f, pb1 = 0.f;
        #pragma unroll
        for (int t = 0; t < 8; t++) {
            pa0 = fmaf(f0[t], r0[t], pa0);
            pb0 = fmaf(f1[t], r0[t], pb0);
            pa1 = fmaf(f0[t], r1[t], pa1);
            pb1 = fmaf(f1[t], r1[t], pb1);
        }
        int  m0c = U0.y, m1c = U1.y;   // carry meta for the write step
        bool h1c = has1;

        // prefetch next iteration (loads fly during the shuffle chain)
        ii += 16;
        bool nact = ii < nu;
        if (nact) {
            U0 = s_u[ii];
            has1 = (ii + 1) < nu;
            U1 = has1 ? s_u[ii + 1] : U0;
            const char* rp0 = rbj + U0.x;
            const char* rp1 = rbj + U1.x;
            #pragma unroll
            for (int t = 0; t < 8; t++) {
                r0[t] = *(const float*)(rp0 + 128 * t);
                r1[t] = *(const float*)(rp1 + 128 * t);
            }
        }

        // butterfly xor 8,16,4,2,1 — order unchanged
        pa0 = __fadd_rn(pa0, __shfl_xor(pa0, 8));
        pb0 = __fadd_rn(pb0, __shfl_xor(pb0, 8));
        pa1 = __fadd_rn(pa1, __shfl_xor(pa1, 8));
        pb1 = __fadd_rn(pb1, __shfl_xor(pb1, 8));
        pa0 = __fadd_rn(pa0, __shfl_xor(pa0, 16));
        pb0 = __fadd_rn(pb0, __shfl_xor(pb0, 16));
        pa1 = __fadd_rn(pa1, __shfl_xor(pa1, 16));
        pb1 = __fadd_rn(pb1, __shfl_xor(pb1, 16));
        pa0 = __fadd_rn(pa0, __shfl_xor(pa0, 4));
        pb0 = __fadd_rn(pb0, __shfl_xor(pb0, 4));
        pa1 = __fadd_rn(pa1, __shfl_xor(pa1, 4));
        pb1 = __fadd_rn(pb1, __shfl_xor(pb1, 4));
        pa0 = __fadd_rn(pa0, __shfl_xor(pa0, 2));
        pb0 = __fadd_rn(pb0, __shfl_xor(pb0, 2));
        pa1 = __fadd_rn(pa1, __shfl_xor(pa1, 2));
        pb1 = __fadd_rn(pb1, __shfl_xor(pb1, 2));
        pa0 = __fadd_rn(pa0, __shfl_xor(pa0, 1));
        pb0 = __fadd_rn(pb0, __shfl_xor(pb0, 1));
        pa1 = __fadd_rn(pa1, __shfl_xor(pa1, 1));
        pb1 = __fadd_rn(pb1, __shfl_xor(pb1, 1));
        if (j == 0) {
            int k0 = m0c & 255, ux0 = m0c >> 8;
            if (ux0 < 9) s_aff0[k0] = pa0;       // p0's k = (uy,ux)
            if (ux0 > 0) s_aff1[k0 - 1] = pb0;   // p1's k = (uy,ux-1)
            if (h1c) {
                int k1 = m1c & 255, ux1 = m1c >> 8;
                if (ux1 < 9) s_aff0[k1] = pa1;
                if (ux1 > 0) s_aff1[k1 - 1] = pb1;
            }
        }
        act = nact;
    }
    __syncthreads();

    // Phase 2: sequential ascending-k fp32 add chain over ALL 81, per pixel.
    if (tid < 2) {
        const float* sa = tid ? s_aff1 : s_aff0;
        float s = 0.f;
        for (int k = 0; k < K2; k++) s = __fadd_rn(s, sa[k]);
        float d = __fadd_rn(s, 1e-7f);
        if (tid) s_den1 = d; else s_den0 = d;
    }
    __syncthreads();

    // Per-union coefficients (boundary entries get exact +0.0f).
    if (tid < nu) {
        int2 uu = s_u[tid];
        int k0 = uu.y & 255, ux = uu.y >> 8;
        s_po[tid] = uu.x;
        s_c0[tid] = (ux < 9) ? __fdiv_rn(s_aff0[k0], s_den0) : 0.f;
        s_c1[tid] = (ux > 0) ? __fdiv_rn(s_aff1[k0 - 1], s_den1) : 0.f;
    }
    __syncthreads();

    // Phase 3: ascending union list = ascending k per pixel; each loaded
    // value feeds both pixels' FMA chains.  8-deep load batches.
    const char* rbc = (const char*)rb + ((size_t)tid << 2);
    float a0 = 0.f, a1 = 0.f;
    int i = 0;
    for (; i + 8 <= nu; i += 8) {
        float4 cA0 = *(const float4*)&s_c0[i];
        float4 cA1 = *(const float4*)&s_c0[i + 4];
        float4 cB0 = *(const float4*)&s_c1[i];
        float4 cB1 = *(const float4*)&s_c1[i + 4];
        int4   poA = *(const int4*)&s_po[i];
        int4   poB = *(const int4*)&s_po[i + 4];
        float v0 = *(const float*)(rbc + poA.x);
        float v1 = *(const float*)(rbc + poA.y);
        float v2 = *(const float*)(rbc + poA.z);
        float v3 = *(const float*)(rbc + poA.w);
        float v4 = *(const float*)(rbc + poB.x);
        float v5 = *(const float*)(rbc + poB.y);
        float v6 = *(const float*)(rbc + poB.z);
        float v7 = *(const float*)(rbc + poB.w);
        a0 = fmaf(cA0.x, v0, a0);  a1 = fmaf(cB0.x, v0, a1);
        a0 = fmaf(cA0.y, v1, a0);  a1 = fmaf(cB0.y, v1, a1);
        a0 = fmaf(cA0.z, v2, a0);  a1 = fmaf(cB0.z, v2, a1);
        a0 = fmaf(cA0.w, v3, a0);  a1 = fmaf(cB0.w, v3, a1);
        a0 = fmaf(cA1.x, v4, a0);  a1 = fmaf(cB1.x, v4, a1);
        a0 = fmaf(cA1.y, v5, a0);  a1 = fmaf(cB1.y, v5, a1);
        a0 = fmaf(cA1.z, v6, a0);  a1 = fmaf(cB1.z, v6, a1);
        a0 = fmaf(cA1.w, v7, a0);  a1 = fmaf(cB1.w, v7, a1);
    }
    if (i + 4 <= nu) {
        float4 cA = *(const float4*)&s_c0[i];
        float4 cB = *(const float4*)&s_c1[i];
        int4   po = *(const int4*)&s_po[i];
        float v0 = *(const float*)(rbc + po.x);
        float v1 = *(const float*)(rbc + po.y);
        float v2 = *(const float*)(rbc + po.z);
        float v3 = *(const float*)(rbc + po.w);
        a0 = fmaf(cA.x, v0, a0);  a1 = fmaf(cB.x, v0, a1);
        a0 = fmaf(cA.y, v1, a0);  a1 = fmaf(cB.y, v1, a1);
        a0 = fmaf(cA.z, v2, a0);  a1 = fmaf(cB.z, v2, a1);
        a0 = fmaf(cA.w, v3, a0);  a1 = fmaf(cB.w, v3, a1);
        i += 4;
    }
    for (; i < nu; i++) {
        float v = *(const float*)(rbc + s_po[i]);
        a0 = fmaf(s_c0[i], v, a0);
        a1 = fmaf(s_c1[i], v, a1);
    }
    alignedT[((size_t)bp << 8) + tid]       = a0;
    alignedT[((size_t)(bp + 1) << 8) + tid] = a1;
}

// ---------------------------------------------------------------------------
// Conv1: 1x1, 512 -> 256, FP32 GEMM (numerics-free; same acc chain order as
// R13: kc ascending, k ascending).
// R18: double-buffered LDS + async-stage split — next K-slab's global loads
// issue BEFORE the 512-FMA compute loop (latency hidden under compute), LDS
// writes land after it; ONE barrier per kc (was two).  LDS 35 KB -> still
// 2 blocks/CU.
// ---------------------------------------------------------------------------
__global__ void k_conv1(const float* __restrict__ featT,
                        const float* __restrict__ alignedT,
                        const float* __restrict__ w1t,
                        const float* __restrict__ b1,
                        float* __restrict__ h1) {
    __shared__ float s_a[2][32][68];     // [buf][k][px]
    __shared__ float s_b[2][32][68];     // [buf][k][o]
    int m0  = blockIdx.x * 64;        // pixel base
    int n0  = blockIdx.y * 64;        // out-channel base
    int tid = threadIdx.x;
    int tx  = tid & 15;               // o quad
    int ty  = tid >> 4;               // px quad
    int cq  = tid & 7;                // a-stage: c quad
    int pxa = tid >> 3;               // a-stage: px 0..31
    int oq  = tid & 15;               // b-stage: o quad
    int cc  = tid >> 4;               // b-stage: c 0..15

    float acc[4][4] = {{0.f}};
    float4 ra0, ra1, rb0, rb1;

#define C1_LOAD(kc_) do {                                                     \
        int c0_ = (kc_) * 32;                                                 \
        const float* asrc_ = (c0_ < 256) ? featT : alignedT;                  \
        int coff_ = (c0_ < 256) ? c0_ : c0_ - 256;                            \
        ra0 = *(const float4*)(asrc_ + ((size_t)(m0 + pxa) << 8) + coff_ + (cq << 2));      \
        ra1 = *(const float4*)(asrc_ + ((size_t)(m0 + 32 + pxa) << 8) + coff_ + (cq << 2)); \
        rb0 = *(const float4*)(w1t + (size_t)(c0_ + cc) * 256 + n0 + (oq << 2));            \
        rb1 = *(const float4*)(w1t + (size_t)(c0_ + 16 + cc) * 256 + n0 + (oq << 2));       \
    } while (0)

#define C1_WRITE(bf_) do {                                                    \
        s_a[bf_][cq * 4 + 0][pxa] = ra0.x;                                    \
        s_a[bf_][cq * 4 + 1][pxa] = ra0.y;                                    \
        s_a[bf_][cq * 4 + 2][pxa] = ra0.z;                                    \
        s_a[bf_][cq * 4 + 3][pxa] = ra0.w;                                    \
        s_a[bf_][cq * 4 + 0][32 + pxa] = ra1.x;                               \
        s_a[bf_][cq * 4 + 1][32 + pxa] = ra1.y;                               \
        s_a[bf_][cq * 4 + 2][32 + pxa] = ra1.z;                               \
        s_a[bf_][cq * 4 + 3][32 + pxa] = ra1.w;                               \
        *(float4*)&s_b[bf_][cc][oq << 2] = rb0;                               \
        *(float4*)&s_b[bf_][16 + cc][oq << 2] = rb1;                          \
    } while (0)

    C1_LOAD(0);
    C1_WRITE(0);
    __syncthreads();

    for (int kc = 0; kc < 16; kc++) {
        int cur = kc & 1;
        if (kc < 15) C1_LOAD(kc + 1);     // loads fly during compute

        #pragma unroll 8
        for (int k = 0; k < 32; k++) {
            float4 av = *(const float4*)&s_a[cur][k][ty << 2];
            float4 bv = *(const float4*)&s_b[cur][k][tx << 2];
            acc[0][0] = fmaf(av.x, bv.x, acc[0][0]);
            acc[0][1] = fmaf(av.x, bv.y, acc[0][1]);
            acc[0][2] = fmaf(av.x, bv.z, acc[0][2]);
            acc[0][3] = fmaf(av.x, bv.w, acc[0][3]);
            acc[1][0] = fmaf(av.y, bv.x, acc[1][0]);
            acc[1][1] = fmaf(av.y, bv.y, acc[1][1]);
            acc[1][2] = fmaf(av.y, bv.z, acc[1][2]);
            acc[1][3] = fmaf(av.y, bv.w, acc[1][3]);
            acc[2][0] = fmaf(av.z, bv.x, acc[2][0]);
            acc[2][1] = fmaf(av.z, bv.y, acc[2][1]);
            acc[2][2] = fmaf(av.z, bv.z, acc[2][2]);
            acc[2][3] = fmaf(av.z, bv.w, acc[2][3]);
            acc[3][0] = fmaf(av.w, bv.x, acc[3][0]);
            acc[3][1] = fmaf(av.w, bv.y, acc[3][1]);
            acc[3][2] = fmaf(av.w, bv.z, acc[3][2]);
            acc[3][3] = fmaf(av.w, bv.w, acc[3][3]);
        }

        if (kc < 15) C1_WRITE(cur ^ 1);
        __syncthreads();
    }

    float4 bias = *(const float4*)(b1 + n0 + tx * 4);
    #pragma unroll
    for (int i = 0; i < 4; i++) {
        int px = m0 + ty * 4 + i;
        float4 v;
        v.x = acc[i][0] + bias.x;
        v.y = acc[i][1] + bias.y;
        v.z = acc[i][2] + bias.z;
        v.w = acc[i][3] + bias.w;
        *(float4*)(h1 + ((size_t)px << 8) + n0 + tx * 4) = v;
    }
}

// ---------------------------------------------------------------------------
// Conv2: 3x3 pad1, 256 -> 16, FP32, numerics-free.  Verbatim from R12.
// ---------------------------------------------------------------------------
__global__ void k_conv2(const float* __restrict__ h1,
                        const float* __restrict__ w2t,
                        const float* __restrict__ b2,
                        float* __restrict__ h2) {
    __shared__ float s_in[3][18][68];
    int blk = blockIdx.x;          // 0..511
    int b   = blk >> 8;            // 256 blocks per batch
    int r   = blk & 255;
    int y   = r >> 2;
    int w0  = (r & 3) * 16;
    int tid = threadIdx.x;
    int o   = tid & 15;
    int ps  = (tid >> 4) & 7;      // slot 0..7 -> pixels ps, ps+8

    const float* hb = h1 + ((size_t)b << 20);

    float4 a0 = {0.f, 0.f, 0.f, 0.f};
    float4 a1 = {0.f, 0.f, 0.f, 0.f};

    for (int chunk = 0; chunk < 4; chunk++) {
        int c0 = chunk << 6;
        for (int i = tid; i < 3 * 18 * 16; i += 256) {
            int c4 = i & 15;
            int pi = (i >> 4) % 18;
            int ri = (i >> 4) / 18;
            int yy = y + ri - 1;
            int xx = w0 + pi - 1;
            float4 v = {0.f, 0.f, 0.f, 0.f};
            if ((unsigned)yy < 64u && (unsigned)xx < 64u)
                v = *(const float4*)(hb + ((size_t)((yy << 6) | xx) << 8) + c0 + (c4 << 2));
            *(float4*)&s_in[ri][pi][c4 << 2] = v;
        }
        __syncthreads();

        #pragma unroll
        for (int kk = 0; kk < 9; kk++) {
            int ky = kk / 3, kx = kk - ky * 3;
            const float* wp = w2t + (((size_t)(kk * 64 + (c0 >> 2)) * 16 + o) << 2);
            #pragma unroll 8
            for (int c4 = 0; c4 < 16; c4++) {
                float4 wv = *(const float4*)(wp + (c4 << 6));
                float4 i0 = *(const float4*)&s_in[ky][ps + kx][c4 << 2];
                float4 i1 = *(const float4*)&s_in[ky][ps + 8 + kx][c4 << 2];
                a0.x = fmaf(wv.x, i0.x, a0.x);
                a0.y = fmaf(wv.y, i0.y, a0.y);
                a0.z = fmaf(wv.z, i0.z, a0.z);
                a0.w = fmaf(wv.w, i0.w, a0.w);
                a1.x = fmaf(wv.x, i1.x, a1.x);
                a1.y = fmaf(wv.y, i1.y, a1.y);
                a1.z = fmaf(wv.z, i1.z, a1.z);
                a1.w = fmaf(wv.w, i1.w, a1.w);
            }
        }
        __syncthreads();
    }

    size_t bp0 = ((size_t)b << 12) + (y << 6) + w0;
    h2[(bp0 + ps) * 16 + o]     = ((a0.x + a0.y) + (a0.z + a0.w)) + b2[o];
    h2[(bp0 + ps + 8) * 16 + o] = ((a1.x + a1.y) + (a1.z + a1.w)) + b2[o];
}

// ---------------------------------------------------------------------------
// Conv3: 3x3 pad1, 16 -> 3, FP32, numerics-free.  Thread per pixel.
// ---------------------------------------------------------------------------
__global__ void k_conv3(const float* __restrict__ h2,
                        const float* __restrict__ w3,
                        const float* __restrict__ b3,
                        float* __restrict__ h3) {
    int bp = blockIdx.x * 256 + threadIdx.x;
    if (bp >= BP_N) return;
    int b = bp >> 12;
    int p = bp & 4095;
    int h = p >> 6, w = p & 63;
    const float* hb = h2 + ((size_t)b << 16);   // b*4096*16

    float a0 = 0.f, a1 = 0.f, a2 = 0.f;
    #pragma unroll
    for (int kk = 0; kk < 9; kk++) {
        int ky = kk / 3, kx = kk - ky * 3;
        int y = h + ky - 1, x = w + kx - 1;
        if ((unsigned)y >= 64u || (unsigned)x >= 64u) continue;
        const float* ip = hb + (size_t)((y << 6) | x) * 16;
        #pragma unroll
        for (int c = 0; c < 16; c++) {
            float v = ip[c];
            int wi = c * 9 + kk;
            a0 = fmaf(w3[wi],       v, a0);
            a1 = fmaf(w3[144 + wi], v, a1);
            a2 = fmaf(w3[288 + wi], v, a2);
        }
    }
    h3[(size_t)bp * 3 + 0] = a0 + b3[0];
    h3[(size_t)bp * 3 + 1] = a1 + b3[1];
    h3[(size_t)bp * 3 + 2] = a2 + b3[2];
}

// ---------------------------------------------------------------------------
// Conv4 (3x3, 3 -> 2) + softmax -> (score0, score1), FP32, numerics-free.
// ---------------------------------------------------------------------------
__global__ void k_score(const float* __restrict__ h3,
                        const float* __restrict__ w4,
                        const float* __restrict__ b4,
                        float2* __restrict__ score) {
    int bp = blockIdx.x * 256 + threadIdx.x;
    if (bp >= BP_N) return;
    int b = bp >> 12;
    int p = bp & 4095;
    int h = p >> 6, w = p & 63;
    const float* hb = h3 + (size_t)b * PIX * 3;

    float l0 = 0.f, l1 = 0.f;
    #pragma unroll
    for (int kk = 0; kk < 9; kk++) {
        int ky = kk / 3, kx = kk - ky * 3;
        int y = h + ky - 1, x = w + kx - 1;
        if ((unsigned)y >= 64u || (unsigned)x >= 64u) continue;
        const float* ip = hb + (size_t)((y << 6) | x) * 3;
        #pragma unroll
        for (int c = 0; c < 3; c++) {
            float v = ip[c];
            int wi = c * 9 + kk;
            l0 = fmaf(w4[wi],      v, l0);
            l1 = fmaf(w4[27 + wi], v, l1);
        }
    }
    l0 += b4[0];
    l1 += b4[1];

    float m  = fmaxf(l0, l1);
    float e0 = expf(l0 - m);
    float e1 = expf(l1 - m);
    float s  = e0 + e1;
    score[bp] = make_float2(e0 / s, e1 / s);
}

// ---------------------------------------------------------------------------
// Blend + on-the-fly NHWC->NCHW transpose of aligned.  Verbatim from R11.
// ---------------------------------------------------------------------------
__global__ void k_blend(const float* __restrict__ feat,
                        const float* __restrict__ alignedT,
                        const float2* __restrict__ score,
                        float* __restrict__ out) {
    __shared__ float tile[32][33];
    int b  = blockIdx.z;
    int p0 = blockIdx.x * 32;
    int c0 = blockIdx.y * 32;
    int tx = threadIdx.x;     // 32
    int ty = threadIdx.y;     // 8

    const float* at = alignedT + ((size_t)b << 20);
    #pragma unroll
    for (int i = 0; i < 4; i++) {
        int p = p0 + ty + i * 8;
        tile[ty + i * 8][tx] = at[((size_t)p << 8) + c0 + tx];
    }
    __syncthreads();

    int p = p0 + tx;
    float2 s = score[(b << 12) + p];
    #pragma unroll
    for (int i = 0; i < 4; i++) {
        int c = c0 + ty + i * 8;
        size_t idx = (((size_t)(b * 256 + c)) << 12) + p;
        out[idx] = __fadd_rn(__fmul_rn(s.x, feat[idx]),
                             __fmul_rn(s.y, tile[tx][ty + i * 8]));
    }
}

// ---------------------------------------------------------------------------
extern "C" void kernel_launch(void* const* d_in, const int* in_sizes, int n_in,
                              void* d_out, int out_size, void* d_ws, size_t ws_size,
                              hipStream_t stream) {
    const float* feat     = (const float*)d_in[0];
    const float* feat_ref = (const float*)d_in[1];
    const float* w1 = (const float*)d_in[2];
    const float* b1 = (const float*)d_in[3];
    const float* w2 = (const float*)d_in[4];
    const float* b2 = (const float*)d_in[5];
    const float* w3 = (const float*)d_in[6];
    const float* b3 = (const float*)d_in[7];
    const float* w4 = (const float*)d_in[8];
    const float* b4 = (const float*)d_in[9];
    float* out = (float*)d_out;

    const size_t NCP = (size_t)BATCH * CCH * PIX;   // 2,097,152
    char* wsb = (char*)d_ws;
    float*  featT    = (float*)wsb;   wsb += NCP * 4;               // 8 MB
    float*  refT     = (float*)wsb;   wsb += NCP * 4;               // 8 MB
    float*  alignedT = (float*)wsb;   wsb += NCP * 4;               // 8 MB
    float*  h1       = (float*)wsb;   wsb += NCP * 4;               // 8 MB
    float*  h2       = (float*)wsb;   wsb += (size_t)BP_N * 16 * 4;
    float*  h3       = (float*)wsb;   wsb += (size_t)BP_N * 3 * 4;
    float2* sc       = (float2*)wsb;  wsb += (size_t)BP_N * 8;
    float*  w2t      = (float*)wsb;   wsb += (size_t)16 * 256 * 9 * 4;
    float*  w1t      = (float*)wsb;   wsb += (size_t)512 * 256 * 4;

    dim3 tb(32, 8, 1);
    k_transpose2<<<dim3(PIX / 32, CCH / 32, 4), tb, 0, stream>>>(feat, feat_ref, featT, refT);
    k_wprep<<<272, 256, 0, stream>>>(w1, w1t, w2, w2t);

    k_corr_assemble<<<BP_N / 2, 256, 0, stream>>>(featT, refT, alignedT);
    k_conv1<<<dim3(BP_N / 64, 256 / 64, 1), 256, 0, stream>>>(featT, alignedT, w1t, b1, h1);
    k_conv2<<<BP_N / 16, 256, 0, stream>>>(h1, w2t, b2, h2);
    k_conv3<<<BP_N / 256, 256, 0, stream>>>(h2, w3, b3, h3);
    k_score<<<BP_N / 256, 256, 0, stream>>>(h3, w4, b4, sc);
    k_blend<<<dim3(PIX / 32, CCH / 32, BATCH), tb, 0, stream>>>(feat, alignedT, sc, out);
}